// Round 1
// baseline (538.385 us; speedup 1.0000x reference)
//
#include <hip/hip_runtime.h>
#include <math.h>

#define Dn 1024
#define Fn 256
#define Sn 4096
#define Bn 4
#define Mn (Bn*Sn)          // 16384 rows
#define CHn 256             // scan chunk length
#define NCn (Sn/CHn)        // 16 chunks per sequence

typedef __bf16 bf16x8 __attribute__((ext_vector_type(8)));
typedef float  f32x4  __attribute__((ext_vector_type(4)));

__device__ inline unsigned short f2bf(float f) {
  unsigned int u = __float_as_uint(f);
  u += 0x7fffu + ((u >> 16) & 1u);
  return (unsigned short)(u >> 16);
}

__device__ inline void async16(const void* g, void* l) {
  __builtin_amdgcn_global_load_lds(
      (__attribute__((address_space(1))) void*)(g),
      (__attribute__((address_space(3))) void*)(l), 16, 0, 0);
}

// ---------------- weight fp32 -> bf16 conversion (one shot) ----------------
__global__ __launch_bounds__(256) void convert_weights(
    const float* __restrict__ wspec, const float* __restrict__ wfrom,
    const float* __restrict__ w1, const float* __restrict__ w2,
    unsigned short* __restrict__ o_spec, unsigned short* __restrict__ o_from,
    unsigned short* __restrict__ o_w1, unsigned short* __restrict__ o_w2) {
  int i = blockIdx.x * 256 + threadIdx.x;   // grid = 4096*256 = 1048576 threads
  if (i < 524288) {
    o_spec[i] = f2bf(wspec[i]);
    o_from[i] = f2bf(wfrom[i]);
  }
  o_w1[i] = f2bf(w1[i]);
  o_w2[i] = f2bf(w2[i]);
}

// ---------------- LayerNorm: one row (D=1024) per block of 256 -------------
// OUT_BF16=1: write ushort bf16; OUT_BF16=0: write float (in-place safe)
template <int OUT_BF16>
__global__ __launch_bounds__(256) void ln_kernel(
    const float* __restrict__ x, const float* __restrict__ g,
    const float* __restrict__ b, void* __restrict__ out) {
  int row = blockIdx.x, tid = threadIdx.x;
  int wid = tid >> 6, lane = tid & 63;
  float4 v = ((const float4*)(x + (size_t)row * Dn))[tid];
  float s  = v.x + v.y + v.z + v.w;
  float ss = v.x * v.x + v.y * v.y + v.z * v.z + v.w * v.w;
  #pragma unroll
  for (int o = 32; o; o >>= 1) {
    s  += __shfl_down(s, o);
    ss += __shfl_down(ss, o);
  }
  __shared__ float r1[4], r2[4];
  if (lane == 0) { r1[wid] = s; r2[wid] = ss; }
  __syncthreads();
  s  = r1[0] + r1[1] + r1[2] + r1[3];
  ss = r2[0] + r2[1] + r2[2] + r2[3];
  float mu  = s * (1.0f / Dn);
  float var = ss * (1.0f / Dn) - mu * mu;
  float rs  = rsqrtf(var + 1e-5f);
  float4 gv = ((const float4*)g)[tid];
  float4 bv = ((const float4*)b)[tid];
  float o0 = (v.x - mu) * rs * gv.x + bv.x;
  float o1 = (v.y - mu) * rs * gv.y + bv.y;
  float o2 = (v.z - mu) * rs * gv.z + bv.z;
  float o3 = (v.w - mu) * rs * gv.w + bv.w;
  if (OUT_BF16) {
    ushort4 w;
    w.x = f2bf(o0); w.y = f2bf(o1); w.z = f2bf(o2); w.w = f2bf(o3);
    ((ushort4*)out)[(size_t)row * 256 + tid] = w;
  } else {
    float4 w; w.x = o0; w.y = o1; w.z = o2; w.w = o3;
    ((float4*)out)[(size_t)row * 256 + tid] = w;
  }
}

// ---------------- MFMA GEMM, NT: C[m,n] = sum_k A[m,k]*Bw[n,k] -------------
// 128x128 tile, BK=32, 256 threads = 4 waves, each wave 64x64 (4x4 MFMA tiles)
// MODE 0: outF = acc
// MODE 1: bu=acc; e=clip(bu-td,-1,1); corr=bu-sig(ew)*e -> outF(f32)+outH(bf16); atomic sum e^2
// MODE 2: outH = bf16(gelu(acc + bias[col]))  (exact gelu)
// MODE 3: outF = acc + bias[col]
template <int MODE>
__global__ __launch_bounds__(256) void gemm_bt(
    const unsigned short* __restrict__ A, const unsigned short* __restrict__ Bw,
    int K, int N,
    float* __restrict__ outF, unsigned short* __restrict__ outH,
    const float* __restrict__ td, const float* __restrict__ bias,
    const float* __restrict__ ew, float* __restrict__ errAcc) {
  __shared__ unsigned short As[128 * 32];
  __shared__ unsigned short Bs[128 * 32];
  __shared__ float red[4];

  int tid = threadIdx.x;
  int wid = tid >> 6, lane = tid & 63;
  int wm = wid >> 1, wn = wid & 1;
  int quad = lane >> 4, l16 = lane & 15;
  int bm = blockIdx.y, bn = blockIdx.x;

  int r_lo = lane >> 2;        // 0..15
  int c8   = (lane & 3) * 8;   // 0,8,16,24

  const unsigned short* Abase = A + (size_t)bm * 128 * K;
  const unsigned short* Bbase = Bw + (size_t)bn * 128 * K;

  f32x4 acc[4][4] = {};

  for (int k0 = 0; k0 < K; k0 += 32) {
    #pragma unroll
    for (int s = 0; s < 2; ++s) {
      int chunk = s * 4 + wid;          // 0..7, wave-uniform
      int r = chunk * 16 + r_lo;        // row within 128
      async16(Abase + (size_t)r * K + k0 + c8, As + chunk * 512);
      async16(Bbase + (size_t)r * K + k0 + c8, Bs + chunk * 512);
    }
    __syncthreads();
    bf16x8 af[4], bf[4];
    #pragma unroll
    for (int i = 0; i < 4; i++)
      af[i] = *(const bf16x8*)(As + (wm * 64 + i * 16 + l16) * 32 + quad * 8);
    #pragma unroll
    for (int j = 0; j < 4; j++)
      bf[j] = *(const bf16x8*)(Bs + (wn * 64 + j * 16 + l16) * 32 + quad * 8);
    #pragma unroll
    for (int i = 0; i < 4; i++)
      #pragma unroll
      for (int j = 0; j < 4; j++)
        acc[i][j] = __builtin_amdgcn_mfma_f32_16x16x32_bf16(af[i], bf[j], acc[i][j], 0, 0, 0);
    __syncthreads();
  }

  float esum = 0.0f;
  float sigw = 0.0f;
  if (MODE == 1) sigw = 1.0f / (1.0f + expf(-ew[0]));

  #pragma unroll
  for (int i = 0; i < 4; i++) {
    int row_base = bm * 128 + wm * 64 + i * 16 + quad * 4;
    #pragma unroll
    for (int j = 0; j < 4; j++) {
      int col = bn * 128 + wn * 64 + j * 16 + l16;
      #pragma unroll
      for (int r = 0; r < 4; r++) {
        size_t idx = (size_t)(row_base + r) * N + col;
        float v = acc[i][j][r];
        if (MODE == 0) {
          outF[idx] = v;
        } else if (MODE == 1) {
          float e = v - td[idx];
          e = fminf(fmaxf(e, -1.0f), 1.0f);
          float corr = v - sigw * e;
          outF[idx] = corr;
          outH[idx] = f2bf(corr);
          esum += e * e;
        } else if (MODE == 2) {
          float h = v + bias[col];
          float gel = 0.5f * h * (1.0f + erff(h * 0.70710678118654752f));
          outH[idx] = f2bf(gel);
        } else {
          outF[idx] = v + bias[col];
        }
      }
    }
  }

  if (MODE == 1) {
    #pragma unroll
    for (int o = 32; o; o >>= 1) esum += __shfl_down(esum, o);
    if (lane == 0) red[wid] = esum;
    __syncthreads();
    if (tid == 0) atomicAdd(errAcc, red[0] + red[1] + red[2] + red[3]);
  }
}

// ---------------- chunked complex scan:  s = A*s + u,  y = rot*s -----------
// spec layout: [Mn, 512] f32, u_re = spec[.., f], u_im = spec[.., 256+f]
__global__ __launch_bounds__(256) void scan_partial(
    const float* __restrict__ spec, const float* __restrict__ log_decay,
    const float* __restrict__ freq, float2* __restrict__ chunkfin) {
  int f = threadIdx.x;
  int bx = blockIdx.x;            // b*NCn + c
  int b = bx / NCn, c = bx % NCn;
  float dec = 1.0f / (1.0f + expf(-log_decay[f]));
  float om  = tanhf(freq[f]) * 0.1f;
  float Are = dec * cosf(om), Aim = dec * sinf(om);
  const float* u = spec + ((size_t)b * Sn + (size_t)c * CHn) * 512 + f;
  float sre = 0.0f, sim = 0.0f;
  for (int t = 0; t < CHn; t++) {
    float ure = u[(size_t)t * 512];
    float uim = u[(size_t)t * 512 + 256];
    float nre = Are * sre - Aim * sim + ure;
    float nim = Are * sim + Aim * sre + uim;
    sre = nre; sim = nim;
  }
  chunkfin[(size_t)bx * 256 + f] = make_float2(sre, sim);
}

__global__ __launch_bounds__(256) void scan_carry(
    const float* __restrict__ log_decay, const float* __restrict__ freq,
    const float2* __restrict__ chunkfin, float2* __restrict__ carries) {
  int f = threadIdx.x;
  int b = blockIdx.x;
  float dec = 1.0f / (1.0f + expf(-log_decay[f]));
  float om  = tanhf(freq[f]) * 0.1f;
  float pre = dec * cosf(om), pim = dec * sinf(om);
  #pragma unroll
  for (int i = 0; i < 8; i++) {      // A^(2^8) = A^CHn
    float nr = pre * pre - pim * pim;
    float ni = 2.0f * pre * pim;
    pre = nr; pim = ni;
  }
  float sre = 0.0f, sim = 0.0f;
  for (int c = 0; c < NCn; c++) {
    carries[(size_t)(b * NCn + c) * 256 + f] = make_float2(sre, sim);
    float2 cf = chunkfin[(size_t)(b * NCn + c) * 256 + f];
    float nre = pre * sre - pim * sim + cf.x;
    float nim = pre * sim + pim * sre + cf.y;
    sre = nre; sim = nim;
  }
}

__global__ __launch_bounds__(256) void scan_final(
    const float* __restrict__ spec, const float* __restrict__ log_decay,
    const float* __restrict__ freq, const float2* __restrict__ carries,
    unsigned short* __restrict__ outH) {
  int f = threadIdx.x;
  int bx = blockIdx.x;
  int b = bx / NCn, c = bx % NCn;
  float dec = 1.0f / (1.0f + expf(-log_decay[f]));
  float om  = tanhf(freq[f]) * 0.1f;
  float Are = dec * cosf(om), Aim = dec * sinf(om);
  float Rre = cosf(om), Rim = sinf(om);
  float2 s0 = carries[(size_t)bx * 256 + f];
  float sre = s0.x, sim = s0.y;
  const float* u = spec + ((size_t)b * Sn + (size_t)c * CHn) * 512 + f;
  unsigned short* o = outH + ((size_t)b * Sn + (size_t)c * CHn) * 512 + f;
  for (int t = 0; t < CHn; t++) {
    float ure = u[(size_t)t * 512];
    float uim = u[(size_t)t * 512 + 256];
    float nre = Are * sre - Aim * sim + ure;
    float nim = Are * sim + Aim * sre + uim;
    sre = nre; sim = nim;
    o[(size_t)t * 512]       = f2bf(Rre * sre - Rim * sim);
    o[(size_t)t * 512 + 256] = f2bf(Rre * sim + Rim * sre);
  }
}

__global__ void finalize_err(const float* __restrict__ errAcc, float* __restrict__ out) {
  float m = errAcc[0] * (1.0f / 16777216.0f);   // / (Mn*Dn)
  out[0] = fminf(fmaxf(m, 0.0f), 1.0f);
}

// ---------------------------------------------------------------------------
extern "C" void kernel_launch(void* const* d_in, const int* in_sizes, int n_in,
                              void* d_out, int out_size, void* d_ws, size_t ws_size,
                              hipStream_t stream) {
  (void)in_sizes; (void)n_in; (void)out_size; (void)ws_size;
  const float* x     = (const float*)d_in[0];
  const float* td    = (const float*)d_in[1];
  const float* wspec = (const float*)d_in[2];
  const float* logd  = (const float*)d_in[3];
  const float* freq  = (const float*)d_in[4];
  const float* wfrom = (const float*)d_in[5];
  const float* g1    = (const float*)d_in[6];
  const float* b1ln  = (const float*)d_in[7];
  const float* W1    = (const float*)d_in[8];
  const float* b1    = (const float*)d_in[9];
  const float* W2    = (const float*)d_in[10];
  const float* b2    = (const float*)d_in[11];
  const float* g2    = (const float*)d_in[12];
  const float* b2ln  = (const float*)d_in[13];
  const float* ew    = (const float*)d_in[14];

  char* ws = (char*)d_ws;
  size_t off = 0;
  float* errAcc = (float*)(ws + off);              off += 256;
  unsigned short* wspec_h = (unsigned short*)(ws + off); off += (size_t)512 * 1024 * 2;
  unsigned short* wfrom_h = (unsigned short*)(ws + off); off += (size_t)1024 * 512 * 2;
  unsigned short* w1_h    = (unsigned short*)(ws + off); off += (size_t)1024 * 1024 * 2;
  unsigned short* w2_h    = (unsigned short*)(ws + off); off += (size_t)1024 * 1024 * 2;
  // region A (32MB): xn_h [LN1->G0], then corr_h [G1->G2]
  unsigned short* xn_h   = (unsigned short*)(ws + off);
  unsigned short* corr_h = (unsigned short*)(ws + off); off += (size_t)Mn * 1024 * 2;
  // region B (32MB): spec f32 [G0->scan_final], then h1_h [G2->G3]
  float* spec          = (float*)(ws + off);
  unsigned short* h1_h = (unsigned short*)(ws + off);  off += (size_t)Mn * 512 * 4;
  // region C (16MB): so_h [scan_final->G1]
  unsigned short* so_h = (unsigned short*)(ws + off);  off += (size_t)Mn * 512 * 2;
  float2* chunkfin = (float2*)(ws + off);              off += (size_t)Bn * NCn * 256 * 8;
  float2* carries  = (float2*)(ws + off);              off += (size_t)Bn * NCn * 256 * 8;

  float* outCorr = (float*)d_out;
  float* outNP   = outCorr + (size_t)Mn * 1024;
  float* outErr  = outNP + (size_t)Mn * 1024;

  hipMemsetAsync(errAcc, 0, 4, stream);
  convert_weights<<<4096, 256, 0, stream>>>(wspec, wfrom, W1, W2,
                                            wspec_h, wfrom_h, w1_h, w2_h);
  ln_kernel<1><<<Mn, 256, 0, stream>>>(x, g1, b1ln, xn_h);
  // spectral = xn @ W_spec^T : [16384,1024] x [512,1024]^T -> [16384,512] f32
  gemm_bt<0><<<dim3(512 / 128, Mn / 128), 256, 0, stream>>>(
      xn_h, wspec_h, 1024, 512, spec, nullptr, nullptr, nullptr, nullptr, nullptr);
  scan_partial<<<Bn * NCn, 256, 0, stream>>>(spec, logd, freq, chunkfin);
  scan_carry<<<Bn, 256, 0, stream>>>(logd, freq, chunkfin, carries);
  scan_final<<<Bn * NCn, 256, 0, stream>>>(spec, logd, freq, carries, so_h);
  // bu = so @ W_from^T, fused error/corrected + err^2 reduce
  gemm_bt<1><<<dim3(1024 / 128, Mn / 128), 256, 0, stream>>>(
      so_h, wfrom_h, 512, 1024, outCorr, corr_h, td, nullptr, ew, errAcc);
  // h1 = gelu(corr @ W1^T + b1)
  gemm_bt<2><<<dim3(1024 / 128, Mn / 128), 256, 0, stream>>>(
      corr_h, w1_h, 1024, 1024, nullptr, h1_h, nullptr, b1, nullptr, nullptr);
  // h2 = h1 @ W2^T + b2 -> f32 directly into d_out's next_prediction region
  gemm_bt<3><<<dim3(1024 / 128, Mn / 128), 256, 0, stream>>>(
      h1_h, w2_h, 1024, 1024, outNP, nullptr, nullptr, b2, nullptr, nullptr);
  // LN2 in place
  ln_kernel<0><<<Mn, 256, 0, stream>>>(outNP, g2, b2ln, outNP);
  finalize_err<<<1, 1, 0, stream>>>(errAcc, outErr);
}

// Round 2
// 512.422 us; speedup vs baseline: 1.0507x; 1.0507x over previous
//
#include <hip/hip_runtime.h>
#include <math.h>

#define Dn 1024
#define Fn 256
#define Sn 4096
#define Bn 4
#define Mn (Bn*Sn)          // 16384 rows
#define CHn 256             // scan chunk length
#define NCn (Sn/CHn)        // 16 chunks per sequence

typedef __bf16 bf16x8 __attribute__((ext_vector_type(8)));
typedef float  f32x4  __attribute__((ext_vector_type(4)));

__device__ inline unsigned short f2bf(float f) {
  unsigned int u = __float_as_uint(f);
  u += 0x7fffu + ((u >> 16) & 1u);
  return (unsigned short)(u >> 16);
}
__device__ inline float bf2f(unsigned short s) {
  return __uint_as_float(((unsigned int)s) << 16);
}

__device__ inline void async16(const void* g, void* l) {
  __builtin_amdgcn_global_load_lds(
      (__attribute__((address_space(1))) void*)(g),
      (__attribute__((address_space(3))) void*)(l), 16, 0, 0);
}

// wait until at most n vector-memory ops outstanding; don't touch lgkm/exp
#define WAITVM(n) __builtin_amdgcn_s_waitcnt(0xF70 | (n))
// raw barrier with memory clobber: no compiler-inserted vmcnt(0) drain,
// and LDS reads can't be hoisted above it
#define BARRIER() asm volatile("s_barrier" ::: "memory")

// ---------------- weight fp32 -> bf16 conversion (one shot) ----------------
__global__ __launch_bounds__(256) void convert_weights(
    const float* __restrict__ wspec, const float* __restrict__ wfrom,
    const float* __restrict__ w1, const float* __restrict__ w2,
    unsigned short* __restrict__ o_spec, unsigned short* __restrict__ o_from,
    unsigned short* __restrict__ o_w1, unsigned short* __restrict__ o_w2) {
  int i = blockIdx.x * 256 + threadIdx.x;   // grid = 4096*256 = 1048576 threads
  if (i < 524288) {
    o_spec[i] = f2bf(wspec[i]);
    o_from[i] = f2bf(wfrom[i]);
  }
  o_w1[i] = f2bf(w1[i]);
  o_w2[i] = f2bf(w2[i]);
}

// ---------------- LayerNorm: one row (D=1024) per block of 256 -------------
template <int OUT_BF16>
__global__ __launch_bounds__(256) void ln_kernel(
    const float* __restrict__ x, const float* __restrict__ g,
    const float* __restrict__ b, void* __restrict__ out) {
  int row = blockIdx.x, tid = threadIdx.x;
  int wid = tid >> 6, lane = tid & 63;
  float4 v = ((const float4*)(x + (size_t)row * Dn))[tid];
  float s  = v.x + v.y + v.z + v.w;
  float ss = v.x * v.x + v.y * v.y + v.z * v.z + v.w * v.w;
  #pragma unroll
  for (int o = 32; o; o >>= 1) {
    s  += __shfl_down(s, o);
    ss += __shfl_down(ss, o);
  }
  __shared__ float r1[4], r2[4];
  if (lane == 0) { r1[wid] = s; r2[wid] = ss; }
  __syncthreads();
  s  = r1[0] + r1[1] + r1[2] + r1[3];
  ss = r2[0] + r2[1] + r2[2] + r2[3];
  float mu  = s * (1.0f / Dn);
  float var = ss * (1.0f / Dn) - mu * mu;
  float rs  = rsqrtf(var + 1e-5f);
  float4 gv = ((const float4*)g)[tid];
  float4 bv = ((const float4*)b)[tid];
  float o0 = (v.x - mu) * rs * gv.x + bv.x;
  float o1 = (v.y - mu) * rs * gv.y + bv.y;
  float o2 = (v.z - mu) * rs * gv.z + bv.z;
  float o3 = (v.w - mu) * rs * gv.w + bv.w;
  if (OUT_BF16) {
    ushort4 w;
    w.x = f2bf(o0); w.y = f2bf(o1); w.z = f2bf(o2); w.w = f2bf(o3);
    ((ushort4*)out)[(size_t)row * 256 + tid] = w;
  } else {
    float4 w; w.x = o0; w.y = o1; w.z = o2; w.w = o3;
    ((float4*)out)[(size_t)row * 256 + tid] = w;
  }
}

// ---------------- MFMA GEMM, NT: C[m,n] = sum_k A[m,k]*Bw[n,k] -------------
// 128x128 tile, BK=32, 256 threads = 4 waves, each wave 64x64 (4x4 MFMA tiles)
// Triple-buffered LDS, depth-2 async prefetch, one raw barrier per K-iter.
// MODE 0: outH = bf16(acc)
// MODE 1: bu=acc; e=clip(bu-td,-1,1); corr=bu-sig(ew)*e -> outF(f32)+outH(bf16); atomic sum e^2
// MODE 2: outH = bf16(gelu(acc + bias[col]))  (exact gelu)
// MODE 3: outF = acc + bias[col]
template <int MODE>
__global__ __launch_bounds__(256) void gemm_bt(
    const unsigned short* __restrict__ A, const unsigned short* __restrict__ Bw,
    int K, int N,
    float* __restrict__ outF, unsigned short* __restrict__ outH,
    const float* __restrict__ td, const float* __restrict__ bias,
    const float* __restrict__ ew, float* __restrict__ errAcc) {
  __shared__ unsigned short As[3 * 4096];   // 3 stages x 128x32
  __shared__ unsigned short Bs[3 * 4096];
  __shared__ float red[4];

  int tid = threadIdx.x;
  int wid = tid >> 6, lane = tid & 63;
  int wm = wid >> 1, wn = wid & 1;
  int quad = lane >> 4, l16 = lane & 15;

  // XCD-aware swizzle: the 8 blocks sharing an A row-block all have the same
  // (g % 8) => land on the same XCD => A-tile is fetched once per XCD L2.
  int g = blockIdx.x + gridDim.x * blockIdx.y;
  int nbn = gridDim.x;
  int gh = g >> 3;
  int bn = gh % nbn;
  int bm = (g & 7) + (gh / nbn) * 8;

  int r_lo = lane >> 2;        // 0..15
  int c8   = (lane & 3) * 8;   // 0,8,16,24

  const unsigned short* Abase = A + (size_t)bm * 128 * K;
  const unsigned short* Bbase = Bw + (size_t)bn * 128 * K;

  f32x4 acc[4][4] = {};

  const int T = K >> 5;
  auto issue = [&](int t, int stg) {
    int k0 = t << 5;
    #pragma unroll
    for (int s = 0; s < 2; ++s) {
      int chunk = s * 4 + wid;          // 0..7, wave-uniform
      int r = chunk * 16 + r_lo;        // row within 128
      async16(Abase + (size_t)r * K + k0 + c8, As + stg * 4096 + chunk * 512);
      async16(Bbase + (size_t)r * K + k0 + c8, Bs + stg * 4096 + chunk * 512);
    }
  };

  issue(0, 0);
  if (T > 1) issue(1, 1);

  int stg = 0, stg2 = 2;
  for (int k = 0; k < T; ++k) {
    // retire tile k's 4 loads (tile k+1's 4 may stay in flight)
    if (k + 1 < T) WAITVM(4); else WAITVM(0);
    BARRIER();                       // tile k visible; tile k-1 consumption done
    if (k + 2 < T) issue(k + 2, stg2);

    const unsigned short* Ab = As + stg * 4096;
    const unsigned short* Bb = Bs + stg * 4096;
    bf16x8 af[4], bf[4];
    #pragma unroll
    for (int i = 0; i < 4; i++)
      af[i] = *(const bf16x8*)(Ab + (wm * 64 + i * 16 + l16) * 32 + quad * 8);
    #pragma unroll
    for (int j = 0; j < 4; j++)
      bf[j] = *(const bf16x8*)(Bb + (wn * 64 + j * 16 + l16) * 32 + quad * 8);
    #pragma unroll
    for (int i = 0; i < 4; i++)
      #pragma unroll
      for (int j = 0; j < 4; j++)
        acc[i][j] = __builtin_amdgcn_mfma_f32_16x16x32_bf16(af[i], bf[j], acc[i][j], 0, 0, 0);

    stg  = (stg  == 2) ? 0 : stg  + 1;
    stg2 = (stg2 == 2) ? 0 : stg2 + 1;
  }

  float esum = 0.0f;
  float sigw = 0.0f;
  if (MODE == 1) sigw = 1.0f / (1.0f + expf(-ew[0]));

  #pragma unroll
  for (int i = 0; i < 4; i++) {
    int row_base = bm * 128 + wm * 64 + i * 16 + quad * 4;
    #pragma unroll
    for (int j = 0; j < 4; j++) {
      int col = bn * 128 + wn * 64 + j * 16 + l16;
      #pragma unroll
      for (int r = 0; r < 4; r++) {
        size_t idx = (size_t)(row_base + r) * N + col;
        float v = acc[i][j][r];
        if (MODE == 0) {
          outH[idx] = f2bf(v);
        } else if (MODE == 1) {
          float e = v - td[idx];
          e = fminf(fmaxf(e, -1.0f), 1.0f);
          float corr = v - sigw * e;
          outF[idx] = corr;
          outH[idx] = f2bf(corr);
          esum += e * e;
        } else if (MODE == 2) {
          float h = v + bias[col];
          float gel = 0.5f * h * (1.0f + erff(h * 0.70710678118654752f));
          outH[idx] = f2bf(gel);
        } else {
          outF[idx] = v + bias[col];
        }
      }
    }
  }

  if (MODE == 1) {
    #pragma unroll
    for (int o = 32; o; o >>= 1) esum += __shfl_down(esum, o);
    if (lane == 0) red[wid] = esum;
    __syncthreads();
    if (tid == 0) atomicAdd(errAcc, red[0] + red[1] + red[2] + red[3]);
  }
}

// ---------------- chunked complex scan:  s = A*s + u,  y = rot*s -----------
// spec layout: [Mn, 512] bf16, u_re = spec[.., f], u_im = spec[.., 256+f]
__global__ __launch_bounds__(256) void scan_partial(
    const unsigned short* __restrict__ spec, const float* __restrict__ log_decay,
    const float* __restrict__ freq, float2* __restrict__ chunkfin) {
  int f = threadIdx.x;
  int bx = blockIdx.x;            // b*NCn + c
  int b = bx / NCn, c = bx % NCn;
  float dec = 1.0f / (1.0f + expf(-log_decay[f]));
  float om  = tanhf(freq[f]) * 0.1f;
  float Are = dec * cosf(om), Aim = dec * sinf(om);
  const unsigned short* u = spec + ((size_t)b * Sn + (size_t)c * CHn) * 512 + f;
  float sre = 0.0f, sim = 0.0f;
  for (int t = 0; t < CHn; t++) {
    float ure = bf2f(u[(size_t)t * 512]);
    float uim = bf2f(u[(size_t)t * 512 + 256]);
    float nre = Are * sre - Aim * sim + ure;
    float nim = Are * sim + Aim * sre + uim;
    sre = nre; sim = nim;
  }
  chunkfin[(size_t)bx * 256 + f] = make_float2(sre, sim);
}

__global__ __launch_bounds__(256) void scan_carry(
    const float* __restrict__ log_decay, const float* __restrict__ freq,
    const float2* __restrict__ chunkfin, float2* __restrict__ carries) {
  int f = threadIdx.x;
  int b = blockIdx.x;
  float dec = 1.0f / (1.0f + expf(-log_decay[f]));
  float om  = tanhf(freq[f]) * 0.1f;
  float pre = dec * cosf(om), pim = dec * sinf(om);
  #pragma unroll
  for (int i = 0; i < 8; i++) {      // A^(2^8) = A^CHn
    float nr = pre * pre - pim * pim;
    float ni = 2.0f * pre * pim;
    pre = nr; pim = ni;
  }
  float sre = 0.0f, sim = 0.0f;
  for (int c = 0; c < NCn; c++) {
    carries[(size_t)(b * NCn + c) * 256 + f] = make_float2(sre, sim);
    float2 cf = chunkfin[(size_t)(b * NCn + c) * 256 + f];
    float nre = pre * sre - pim * sim + cf.x;
    float nim = pre * sim + pim * sre + cf.y;
    sre = nre; sim = nim;
  }
}

__global__ __launch_bounds__(256) void scan_final(
    const unsigned short* __restrict__ spec, const float* __restrict__ log_decay,
    const float* __restrict__ freq, const float2* __restrict__ carries,
    unsigned short* __restrict__ outH) {
  int f = threadIdx.x;
  int bx = blockIdx.x;
  int b = bx / NCn, c = bx % NCn;
  float dec = 1.0f / (1.0f + expf(-log_decay[f]));
  float om  = tanhf(freq[f]) * 0.1f;
  float Are = dec * cosf(om), Aim = dec * sinf(om);
  float Rre = cosf(om), Rim = sinf(om);
  float2 s0 = carries[(size_t)bx * 256 + f];
  float sre = s0.x, sim = s0.y;
  const unsigned short* u = spec + ((size_t)b * Sn + (size_t)c * CHn) * 512 + f;
  unsigned short* o = outH + ((size_t)b * Sn + (size_t)c * CHn) * 512 + f;
  for (int t = 0; t < CHn; t++) {
    float ure = bf2f(u[(size_t)t * 512]);
    float uim = bf2f(u[(size_t)t * 512 + 256]);
    float nre = Are * sre - Aim * sim + ure;
    float nim = Are * sim + Aim * sre + uim;
    sre = nre; sim = nim;
    o[(size_t)t * 512]       = f2bf(Rre * sre - Rim * sim);
    o[(size_t)t * 512 + 256] = f2bf(Rre * sim + Rim * sre);
  }
}

__global__ void finalize_err(const float* __restrict__ errAcc, float* __restrict__ out) {
  float m = errAcc[0] * (1.0f / 16777216.0f);   // / (Mn*Dn)
  out[0] = fminf(fmaxf(m, 0.0f), 1.0f);
}

// ---------------------------------------------------------------------------
extern "C" void kernel_launch(void* const* d_in, const int* in_sizes, int n_in,
                              void* d_out, int out_size, void* d_ws, size_t ws_size,
                              hipStream_t stream) {
  (void)in_sizes; (void)n_in; (void)out_size; (void)ws_size;
  const float* x     = (const float*)d_in[0];
  const float* td    = (const float*)d_in[1];
  const float* wspec = (const float*)d_in[2];
  const float* logd  = (const float*)d_in[3];
  const float* freq  = (const float*)d_in[4];
  const float* wfrom = (const float*)d_in[5];
  const float* g1    = (const float*)d_in[6];
  const float* b1ln  = (const float*)d_in[7];
  const float* W1    = (const float*)d_in[8];
  const float* b1    = (const float*)d_in[9];
  const float* W2    = (const float*)d_in[10];
  const float* b2    = (const float*)d_in[11];
  const float* g2    = (const float*)d_in[12];
  const float* b2ln  = (const float*)d_in[13];
  const float* ew    = (const float*)d_in[14];

  char* ws = (char*)d_ws;
  size_t off = 0;
  float* errAcc = (float*)(ws + off);              off += 256;
  unsigned short* wspec_h = (unsigned short*)(ws + off); off += (size_t)512 * 1024 * 2;
  unsigned short* wfrom_h = (unsigned short*)(ws + off); off += (size_t)1024 * 512 * 2;
  unsigned short* w1_h    = (unsigned short*)(ws + off); off += (size_t)1024 * 1024 * 2;
  unsigned short* w2_h    = (unsigned short*)(ws + off); off += (size_t)1024 * 1024 * 2;
  // region A (32MB): xn_h [LN1->G0], then corr_h [G1->G2]
  unsigned short* xn_h   = (unsigned short*)(ws + off);
  unsigned short* corr_h = (unsigned short*)(ws + off); off += (size_t)Mn * 1024 * 2;
  // region B (32MB): spec bf16 [G0->scan_final], then h1_h [G2->G3]
  unsigned short* spec  = (unsigned short*)(ws + off);
  unsigned short* h1_h  = (unsigned short*)(ws + off);  off += (size_t)Mn * 1024 * 2;
  // region C (16MB): so_h [scan_final->G1]
  unsigned short* so_h = (unsigned short*)(ws + off);  off += (size_t)Mn * 512 * 2;
  float2* chunkfin = (float2*)(ws + off);              off += (size_t)Bn * NCn * 256 * 8;
  float2* carries  = (float2*)(ws + off);              off += (size_t)Bn * NCn * 256 * 8;

  float* outCorr = (float*)d_out;
  float* outNP   = outCorr + (size_t)Mn * 1024;
  float* outErr  = outNP + (size_t)Mn * 1024;

  hipMemsetAsync(errAcc, 0, 4, stream);
  convert_weights<<<4096, 256, 0, stream>>>(wspec, wfrom, W1, W2,
                                            wspec_h, wfrom_h, w1_h, w2_h);
  ln_kernel<1><<<Mn, 256, 0, stream>>>(x, g1, b1ln, xn_h);
  // spectral = xn @ W_spec^T : [16384,1024] x [512,1024]^T -> [16384,512] bf16
  gemm_bt<0><<<dim3(512 / 128, Mn / 128), 256, 0, stream>>>(
      xn_h, wspec_h, 1024, 512, nullptr, spec, nullptr, nullptr, nullptr, nullptr);
  scan_partial<<<Bn * NCn, 256, 0, stream>>>(spec, logd, freq, chunkfin);
  scan_carry<<<Bn, 256, 0, stream>>>(logd, freq, chunkfin, carries);
  scan_final<<<Bn * NCn, 256, 0, stream>>>(spec, logd, freq, carries, so_h);
  // bu = so @ W_from^T, fused error/corrected + err^2 reduce
  gemm_bt<1><<<dim3(1024 / 128, Mn / 128), 256, 0, stream>>>(
      so_h, wfrom_h, 512, 1024, outCorr, corr_h, td, nullptr, ew, errAcc);
  // h1 = gelu(corr @ W1^T + b1)
  gemm_bt<2><<<dim3(1024 / 128, Mn / 128), 256, 0, stream>>>(
      corr_h, w1_h, 1024, 1024, nullptr, h1_h, nullptr, b1, nullptr, nullptr);
  // h2 = h1 @ W2^T + b2 -> f32 directly into d_out's next_prediction region
  gemm_bt<3><<<dim3(1024 / 128, Mn / 128), 256, 0, stream>>>(
      h1_h, w2_h, 1024, 1024, outNP, nullptr, nullptr, b2, nullptr, nullptr);
  // LN2 in place
  ln_kernel<0><<<Mn, 256, 0, stream>>>(outNP, g2, b2ln, outNP);
  finalize_err<<<1, 1, 0, stream>>>(errAcc, outErr);
}

// Round 3
// 480.635 us; speedup vs baseline: 1.1202x; 1.0661x over previous
//
#include <hip/hip_runtime.h>
#include <math.h>

#define Dn 1024
#define Fn 256
#define Sn 4096
#define Bn 4
#define Mn (Bn*Sn)          // 16384 rows
#define CHn 256             // scan chunk length
#define NCn (Sn/CHn)        // 16 chunks per sequence

typedef __bf16 bf16x8 __attribute__((ext_vector_type(8)));
typedef float  f32x4  __attribute__((ext_vector_type(4)));

__device__ inline unsigned short f2bf(float f) {
  unsigned int u = __float_as_uint(f);
  u += 0x7fffu + ((u >> 16) & 1u);
  return (unsigned short)(u >> 16);
}
__device__ inline float bf2f(unsigned short s) {
  return __uint_as_float(((unsigned int)s) << 16);
}

__device__ inline void async16(const void* g, void* l) {
  __builtin_amdgcn_global_load_lds(
      (__attribute__((address_space(1))) void*)(g),
      (__attribute__((address_space(3))) void*)(l), 16, 0, 0);
}

// wait until at most n vector-memory ops outstanding; don't touch lgkm/exp
#define WAITVM(n) __builtin_amdgcn_s_waitcnt(0xF70 | (n))
// raw barrier with memory clobber: no compiler-inserted vmcnt(0) drain
#define BARRIER() asm volatile("s_barrier" ::: "memory")

// ---------------- weight fp32 -> bf16 conversion (one shot) ----------------
__global__ __launch_bounds__(256) void convert_weights(
    const float* __restrict__ wspec, const float* __restrict__ wfrom,
    const float* __restrict__ w1, const float* __restrict__ w2,
    unsigned short* __restrict__ o_spec, unsigned short* __restrict__ o_from,
    unsigned short* __restrict__ o_w1, unsigned short* __restrict__ o_w2) {
  int i = blockIdx.x * 256 + threadIdx.x;   // grid = 4096*256 = 1048576 threads
  if (i < 524288) {
    o_spec[i] = f2bf(wspec[i]);
    o_from[i] = f2bf(wfrom[i]);
  }
  o_w1[i] = f2bf(w1[i]);
  o_w2[i] = f2bf(w2[i]);
}

// ---------------- LayerNorm: one row (D=1024) per block of 256 -------------
// IN_BF16: input is ushort bf16 (else f32). OUT_BF16: output ushort bf16 (else f32)
template <int IN_BF16, int OUT_BF16>
__global__ __launch_bounds__(256) void ln_kernel(
    const void* __restrict__ xin, const float* __restrict__ g,
    const float* __restrict__ b, void* __restrict__ out) {
  int row = blockIdx.x, tid = threadIdx.x;
  int wid = tid >> 6, lane = tid & 63;
  float4 v;
  if (IN_BF16) {
    ushort4 u = ((const ushort4*)xin)[(size_t)row * 256 + tid];
    v.x = bf2f(u.x); v.y = bf2f(u.y); v.z = bf2f(u.z); v.w = bf2f(u.w);
  } else {
    v = ((const float4*)xin)[(size_t)row * 256 + tid];
  }
  float s  = v.x + v.y + v.z + v.w;
  float ss = v.x * v.x + v.y * v.y + v.z * v.z + v.w * v.w;
  #pragma unroll
  for (int o = 32; o; o >>= 1) {
    s  += __shfl_down(s, o);
    ss += __shfl_down(ss, o);
  }
  __shared__ float r1[4], r2[4];
  if (lane == 0) { r1[wid] = s; r2[wid] = ss; }
  __syncthreads();
  s  = r1[0] + r1[1] + r1[2] + r1[3];
  ss = r2[0] + r2[1] + r2[2] + r2[3];
  float mu  = s * (1.0f / Dn);
  float var = ss * (1.0f / Dn) - mu * mu;
  float rs  = rsqrtf(var + 1e-5f);
  float4 gv = ((const float4*)g)[tid];
  float4 bv = ((const float4*)b)[tid];
  float o0 = (v.x - mu) * rs * gv.x + bv.x;
  float o1 = (v.y - mu) * rs * gv.y + bv.y;
  float o2 = (v.z - mu) * rs * gv.z + bv.z;
  float o3 = (v.w - mu) * rs * gv.w + bv.w;
  if (OUT_BF16) {
    ushort4 w;
    w.x = f2bf(o0); w.y = f2bf(o1); w.z = f2bf(o2); w.w = f2bf(o3);
    ((ushort4*)out)[(size_t)row * 256 + tid] = w;
  } else {
    float4 w; w.x = o0; w.y = o1; w.z = o2; w.w = o3;
    ((float4*)out)[(size_t)row * 256 + tid] = w;
  }
}

// ---------------- MFMA GEMM, NT: C[m,n] = sum_k A[m,k]*Bw[n,k] -------------
// 128x128 tile, BK=32, 256 threads = 4 waves, each wave 64x64 (4x4 MFMA tiles)
// Double-buffered LDS (32 KB -> 4 blocks/CU, whole 1024-block grid resident),
// post-barrier depth-1 async prefetch, one raw barrier per K-iter.
// MODE 0: outH = bf16(acc)
// MODE 1: bu=acc; e=clip(bu-td,-1,1); corr=bu-sig(ew)*e -> outF(f32)+outH(bf16); atomic sum e^2
// MODE 2: outH = bf16(gelu(acc + bias[col]))  (exact gelu)
// MODE 3: outF = acc + bias[col]
// MODE 4: outH = bf16(acc + bias[col])
template <int MODE>
__global__ __launch_bounds__(256, 4) void gemm_bt(
    const unsigned short* __restrict__ A, const unsigned short* __restrict__ Bw,
    int K, int N,
    float* __restrict__ outF, unsigned short* __restrict__ outH,
    const float* __restrict__ td, const float* __restrict__ bias,
    const float* __restrict__ ew, float* __restrict__ errAcc) {
  __shared__ unsigned short As[2 * 4096];   // 2 stages x 128x32
  __shared__ unsigned short Bs[2 * 4096];
  __shared__ float red[4];

  int tid = threadIdx.x;
  int wid = tid >> 6, lane = tid & 63;
  int wm = wid >> 1, wn = wid & 1;
  int quad = lane >> 4, l16 = lane & 15;

  // XCD-aware swizzle: the 8 blocks sharing an A row-block all have the same
  // (g % 8) => land on the same XCD => A-tile fetched once per XCD L2.
  int g = blockIdx.x + gridDim.x * blockIdx.y;
  int nbn = gridDim.x;
  int gh = g >> 3;
  int bn = gh % nbn;
  int bm = (g & 7) + (gh / nbn) * 8;

  int r_lo = lane >> 2;        // 0..15
  int c8   = (lane & 3) * 8;   // 0,8,16,24

  const unsigned short* Abase = A + (size_t)bm * 128 * K;
  const unsigned short* Bbase = Bw + (size_t)bn * 128 * K;

  f32x4 acc[4][4] = {};

  const int T = K >> 5;
  auto issue = [&](int t, int stg) {
    int k0 = t << 5;
    #pragma unroll
    for (int s = 0; s < 2; ++s) {
      int chunk = s * 4 + wid;          // 0..7, wave-uniform
      int r = chunk * 16 + r_lo;        // row within 128
      async16(Abase + (size_t)r * K + k0 + c8, As + stg * 4096 + chunk * 512);
      async16(Bbase + (size_t)r * K + k0 + c8, Bs + stg * 4096 + chunk * 512);
    }
  };

  issue(0, 0);

  for (int k = 0; k < T; ++k) {
    WAITVM(0);        // own tile-k loads landed (prefetched a full iter ago)
    BARRIER();        // all waves: tile k visible, tile-(k-1) reads done
    if (k + 1 < T) issue(k + 1, (k + 1) & 1);   // in flight across compute(k)

    const unsigned short* Ab = As + (k & 1) * 4096;
    const unsigned short* Bb = Bs + (k & 1) * 4096;
    bf16x8 af[4], bf[4];
    #pragma unroll
    for (int i = 0; i < 4; i++)
      af[i] = *(const bf16x8*)(Ab + (wm * 64 + i * 16 + l16) * 32 + quad * 8);
    #pragma unroll
    for (int j = 0; j < 4; j++)
      bf[j] = *(const bf16x8*)(Bb + (wn * 64 + j * 16 + l16) * 32 + quad * 8);
    #pragma unroll
    for (int i = 0; i < 4; i++)
      #pragma unroll
      for (int j = 0; j < 4; j++)
        acc[i][j] = __builtin_amdgcn_mfma_f32_16x16x32_bf16(af[i], bf[j], acc[i][j], 0, 0, 0);
  }

  float esum = 0.0f;
  float sigw = 0.0f;
  if (MODE == 1) sigw = 1.0f / (1.0f + expf(-ew[0]));

  #pragma unroll
  for (int i = 0; i < 4; i++) {
    int row_base = bm * 128 + wm * 64 + i * 16 + quad * 4;
    #pragma unroll
    for (int j = 0; j < 4; j++) {
      int col = bn * 128 + wn * 64 + j * 16 + l16;
      #pragma unroll
      for (int r = 0; r < 4; r++) {
        size_t idx = (size_t)(row_base + r) * N + col;
        float v = acc[i][j][r];
        if (MODE == 0) {
          outH[idx] = f2bf(v);
        } else if (MODE == 1) {
          float e = v - td[idx];
          e = fminf(fmaxf(e, -1.0f), 1.0f);
          float corr = v - sigw * e;
          outF[idx] = corr;
          outH[idx] = f2bf(corr);
          esum += e * e;
        } else if (MODE == 2) {
          float h = v + bias[col];
          float gel = 0.5f * h * (1.0f + erff(h * 0.70710678118654752f));
          outH[idx] = f2bf(gel);
        } else if (MODE == 3) {
          outF[idx] = v + bias[col];
        } else {
          outH[idx] = f2bf(v + bias[col]);
        }
      }
    }
  }

  if (MODE == 1) {
    #pragma unroll
    for (int o = 32; o; o >>= 1) esum += __shfl_down(esum, o);
    if (lane == 0) red[wid] = esum;
    __syncthreads();
    if (tid == 0) atomicAdd(errAcc, red[0] + red[1] + red[2] + red[3]);
  }
}

// ---------------- chunked complex scan:  s = A*s + u,  y = rot*s -----------
// spec layout: [Mn, 512] bf16, u_re = spec[.., f], u_im = spec[.., 256+f]
__global__ __launch_bounds__(256) void scan_partial(
    const unsigned short* __restrict__ spec, const float* __restrict__ log_decay,
    const float* __restrict__ freq, float2* __restrict__ chunkfin) {
  int f = threadIdx.x;
  int bx = blockIdx.x;            // b*NCn + c
  int b = bx / NCn, c = bx % NCn;
  float dec = 1.0f / (1.0f + expf(-log_decay[f]));
  float om  = tanhf(freq[f]) * 0.1f;
  float Are = dec * cosf(om), Aim = dec * sinf(om);
  const unsigned short* u = spec + ((size_t)b * Sn + (size_t)c * CHn) * 512 + f;
  float sre = 0.0f, sim = 0.0f;
  for (int t = 0; t < CHn; t++) {
    float ure = bf2f(u[(size_t)t * 512]);
    float uim = bf2f(u[(size_t)t * 512 + 256]);
    float nre = Are * sre - Aim * sim + ure;
    float nim = Are * sim + Aim * sre + uim;
    sre = nre; sim = nim;
  }
  chunkfin[(size_t)bx * 256 + f] = make_float2(sre, sim);
}

__global__ __launch_bounds__(256) void scan_carry(
    const float* __restrict__ log_decay, const float* __restrict__ freq,
    const float2* __restrict__ chunkfin, float2* __restrict__ carries) {
  int f = threadIdx.x;
  int b = blockIdx.x;
  float dec = 1.0f / (1.0f + expf(-log_decay[f]));
  float om  = tanhf(freq[f]) * 0.1f;
  float pre = dec * cosf(om), pim = dec * sinf(om);
  #pragma unroll
  for (int i = 0; i < 8; i++) {      // A^(2^8) = A^CHn
    float nr = pre * pre - pim * pim;
    float ni = 2.0f * pre * pim;
    pre = nr; pim = ni;
  }
  float sre = 0.0f, sim = 0.0f;
  for (int c = 0; c < NCn; c++) {
    carries[(size_t)(b * NCn + c) * 256 + f] = make_float2(sre, sim);
    float2 cf = chunkfin[(size_t)(b * NCn + c) * 256 + f];
    float nre = pre * sre - pim * sim + cf.x;
    float nim = pre * sim + pim * sre + cf.y;
    sre = nre; sim = nim;
  }
}

__global__ __launch_bounds__(256) void scan_final(
    const unsigned short* __restrict__ spec, const float* __restrict__ log_decay,
    const float* __restrict__ freq, const float2* __restrict__ carries,
    unsigned short* __restrict__ outH) {
  int f = threadIdx.x;
  int bx = blockIdx.x;
  int b = bx / NCn, c = bx % NCn;
  float dec = 1.0f / (1.0f + expf(-log_decay[f]));
  float om  = tanhf(freq[f]) * 0.1f;
  float Are = dec * cosf(om), Aim = dec * sinf(om);
  float Rre = cosf(om), Rim = sinf(om);
  float2 s0 = carries[(size_t)bx * 256 + f];
  float sre = s0.x, sim = s0.y;
  const unsigned short* u = spec + ((size_t)b * Sn + (size_t)c * CHn) * 512 + f;
  unsigned short* o = outH + ((size_t)b * Sn + (size_t)c * CHn) * 512 + f;
  for (int t = 0; t < CHn; t++) {
    float ure = bf2f(u[(size_t)t * 512]);
    float uim = bf2f(u[(size_t)t * 512 + 256]);
    float nre = Are * sre - Aim * sim + ure;
    float nim = Are * sim + Aim * sre + uim;
    sre = nre; sim = nim;
    o[(size_t)t * 512]       = f2bf(Rre * sre - Rim * sim);
    o[(size_t)t * 512 + 256] = f2bf(Rre * sim + Rim * sre);
  }
}

__global__ void finalize_err(const float* __restrict__ errAcc, float* __restrict__ out) {
  float m = errAcc[0] * (1.0f / 16777216.0f);   // / (Mn*Dn)
  out[0] = fminf(fmaxf(m, 0.0f), 1.0f);
}

// ---------------------------------------------------------------------------
extern "C" void kernel_launch(void* const* d_in, const int* in_sizes, int n_in,
                              void* d_out, int out_size, void* d_ws, size_t ws_size,
                              hipStream_t stream) {
  (void)in_sizes; (void)n_in; (void)out_size; (void)ws_size;
  const float* x     = (const float*)d_in[0];
  const float* td    = (const float*)d_in[1];
  const float* wspec = (const float*)d_in[2];
  const float* logd  = (const float*)d_in[3];
  const float* freq  = (const float*)d_in[4];
  const float* wfrom = (const float*)d_in[5];
  const float* g1    = (const float*)d_in[6];
  const float* b1ln  = (const float*)d_in[7];
  const float* W1    = (const float*)d_in[8];
  const float* b1    = (const float*)d_in[9];
  const float* W2    = (const float*)d_in[10];
  const float* b2    = (const float*)d_in[11];
  const float* g2    = (const float*)d_in[12];
  const float* b2ln  = (const float*)d_in[13];
  const float* ew    = (const float*)d_in[14];

  char* ws = (char*)d_ws;
  size_t off = 0;
  float* errAcc = (float*)(ws + off);              off += 256;
  unsigned short* wspec_h = (unsigned short*)(ws + off); off += (size_t)512 * 1024 * 2;
  unsigned short* wfrom_h = (unsigned short*)(ws + off); off += (size_t)1024 * 512 * 2;
  unsigned short* w1_h    = (unsigned short*)(ws + off); off += (size_t)1024 * 1024 * 2;
  unsigned short* w2_h    = (unsigned short*)(ws + off); off += (size_t)1024 * 1024 * 2;
  // region A (32MB): xn_h [LN1->G0] -> corr_h [G1->G2] -> h2_h [G3->LN2]
  unsigned short* xn_h   = (unsigned short*)(ws + off);
  unsigned short* corr_h = (unsigned short*)(ws + off);
  unsigned short* h2_h   = (unsigned short*)(ws + off); off += (size_t)Mn * 1024 * 2;
  // region B (32MB): spec bf16 [G0->scan_final] -> h1_h [G2->G3]
  unsigned short* spec  = (unsigned short*)(ws + off);
  unsigned short* h1_h  = (unsigned short*)(ws + off);  off += (size_t)Mn * 1024 * 2;
  // region C (16MB): so_h [scan_final->G1]
  unsigned short* so_h = (unsigned short*)(ws + off);  off += (size_t)Mn * 512 * 2;
  float2* chunkfin = (float2*)(ws + off);              off += (size_t)Bn * NCn * 256 * 8;
  float2* carries  = (float2*)(ws + off);              off += (size_t)Bn * NCn * 256 * 8;

  float* outCorr = (float*)d_out;
  float* outNP   = outCorr + (size_t)Mn * 1024;
  float* outErr  = outNP + (size_t)Mn * 1024;

  hipMemsetAsync(errAcc, 0, 4, stream);
  convert_weights<<<4096, 256, 0, stream>>>(wspec, wfrom, W1, W2,
                                            wspec_h, wfrom_h, w1_h, w2_h);
  ln_kernel<0, 1><<<Mn, 256, 0, stream>>>(x, g1, b1ln, xn_h);
  // spectral = xn @ W_spec^T : [16384,1024] x [512,1024]^T -> [16384,512] bf16
  gemm_bt<0><<<dim3(512 / 128, Mn / 128), 256, 0, stream>>>(
      xn_h, wspec_h, 1024, 512, nullptr, spec, nullptr, nullptr, nullptr, nullptr);
  scan_partial<<<Bn * NCn, 256, 0, stream>>>(spec, logd, freq, chunkfin);
  scan_carry<<<Bn, 256, 0, stream>>>(logd, freq, chunkfin, carries);
  scan_final<<<Bn * NCn, 256, 0, stream>>>(spec, logd, freq, carries, so_h);
  // bu = so @ W_from^T, fused error/corrected + err^2 reduce
  gemm_bt<1><<<dim3(1024 / 128, Mn / 128), 256, 0, stream>>>(
      so_h, wfrom_h, 512, 1024, outCorr, corr_h, td, nullptr, ew, errAcc);
  // h1 = gelu(corr @ W1^T + b1)
  gemm_bt<2><<<dim3(1024 / 128, Mn / 128), 256, 0, stream>>>(
      corr_h, w1_h, 1024, 1024, nullptr, h1_h, nullptr, b1, nullptr, nullptr);
  // h2 = bf16(h1 @ W2^T + b2) -> ws (LN2 consumes bf16, saves 100 MB traffic)
  gemm_bt<4><<<dim3(1024 / 128, Mn / 128), 256, 0, stream>>>(
      h1_h, w2_h, 1024, 1024, nullptr, h2_h, nullptr, b2, nullptr, nullptr);
  // LN2: bf16 in -> f32 out into d_out's next_prediction region
  ln_kernel<1, 0><<<Mn, 256, 0, stream>>>(h2_h, g2, b2ln, outNP);
  finalize_err<<<1, 1, 0, stream>>>(errAcc, outErr);
}